// Round 11
// baseline (702.800 us; speedup 1.0000x reference)
//
#include <hip/hip_runtime.h>
#include <math.h>
#include <stdint.h>

#define NUM_EMB 512
#define EMB_DIM 64
#define BB 16
#define TT 8192
#define BT (BB * TT)               // 131072 positions
#define NSPLIT 4                   // codebook split factor
#define KCHUNK (NUM_EMB / NSPLIT)  // 128 codewords per block
#define KT 32                      // k-tile (accumulators per thread)

typedef float vf4 __attribute__((ext_vector_type(4)));

// ---------------------------------------------------------------------------
// Single fused kernel. blockIdx = pb*4 + quarter. Each block scans 128
// codewords for its 256 positions with a TILED accumulator structure:
//   acc[32] carried across 4 d-chunks of 16 x-values each. Only 16 x-values
//   are live at a time (short ranges -> no spill/remat incentive; r6-r10
//   showed the compiler refuses to keep 64 long-lived x regs). The per-k
//   d-chain still runs d=0..63 strictly sequentially -> bit-exact numpy:
//   acc = fl(acc + fl(x_d*c_d)) (no fma); d_k = fl(fl(A - fl(2E)) + C_k);
//   first-occurrence argmin. Codebook rows via wave-uniform s_load.
// Norms computed block-locally into LDS (numpy pairwise 8-acc pattern).
// Combine fused: last of the 4 sibling blocks (device-scope atomic flag +
// threadfence) picks the u64-min candidate and does the gather + STE write.
// ---------------------------------------------------------------------------
__global__ __launch_bounds__(256, 4) void vq_fused(
    const float* __restrict__ x,
    const float* __restrict__ cb,
    uint64_t* __restrict__ cand,
    uint32_t* __restrict__ flags,
    float* __restrict__ out) {
  __shared__ float nlds[KCHUNK];
  __shared__ int lastFlag;

  const int tid     = threadIdx.x;
  const int quarter = blockIdx.x & (NSPLIT - 1);
  const int pb      = blockIdx.x >> 2;        // position-block
  const int p       = pb * 256 + tid;         // position in [0, B*T)
  const int b       = p >> 13;
  const int t       = p & (TT - 1);
  const int kbase   = quarter * KCHUNK;

  // ---- block-local numpy-pairwise norms for this quarter -> LDS ----
  if (tid < KCHUNK) {
    const float* row = cb + (size_t)(kbase + tid) * EMB_DIM;
    float r[8];
#pragma unroll
    for (int g = 0; g < 8; ++g) {
#pragma unroll
      for (int j = 0; j < 8; ++j) {
        float v = row[g * 8 + j];
        float s = __fmul_rn(v, v);
        r[j] = (g == 0) ? s : __fadd_rn(r[j], s);
      }
    }
    nlds[tid] = __fadd_rn(
        __fadd_rn(__fadd_rn(r[0], r[1]), __fadd_rn(r[2], r[3])),
        __fadd_rn(__fadd_rn(r[4], r[5]), __fadd_rn(r[6], r[7])));
  }
  __syncthreads();

  const float* xb = x + (size_t)b * EMB_DIM * TT + t;

  // ---- A = numpy pairwise sum of squares (8 strided values live at once) ----
  float A;
  {
    float r[8];
#pragma unroll
    for (int g = 0; g < 8; ++g) {
#pragma unroll
      for (int j = 0; j < 8; ++j) {
        float v = xb[(size_t)(g * 8 + j) * TT];
        float s = __fmul_rn(v, v);
        r[j] = (g == 0) ? s : __fadd_rn(r[j], s);
      }
    }
    A = __fadd_rn(
        __fadd_rn(__fadd_rn(r[0], r[1]), __fadd_rn(r[2], r[3])),
        __fadd_rn(__fadd_rn(r[4], r[5]), __fadd_rn(r[6], r[7])));
  }

  float dmin = INFINITY;
  int best = kbase;

  // ---- k-tiles of 32; per tile: 4 d-chunks of 16 x-values ----
  for (int tile = 0; tile < KCHUNK / KT; ++tile) {
    const int k0 = kbase + tile * KT;
    float acc[KT];
#pragma unroll
    for (int kk = 0; kk < KT; ++kk) acc[kk] = 0.f;

#pragma unroll
    for (int dc = 0; dc < 4; ++dc) {
      float xc[16];
#pragma unroll
      for (int j = 0; j < 16; ++j) xc[j] = xb[(size_t)(dc * 16 + j) * TT];

#pragma unroll
      for (int kk = 0; kk < KT; ++kk) {
        const vf4* row = (const vf4*)(cb + (size_t)(k0 + kk) * EMB_DIM + dc * 16);
        vf4 c0 = row[0], c1 = row[1], c2 = row[2], c3 = row[3];
        float a = acc[kk];
        a = __fadd_rn(a, __fmul_rn(xc[0],  c0.x));
        a = __fadd_rn(a, __fmul_rn(xc[1],  c0.y));
        a = __fadd_rn(a, __fmul_rn(xc[2],  c0.z));
        a = __fadd_rn(a, __fmul_rn(xc[3],  c0.w));
        a = __fadd_rn(a, __fmul_rn(xc[4],  c1.x));
        a = __fadd_rn(a, __fmul_rn(xc[5],  c1.y));
        a = __fadd_rn(a, __fmul_rn(xc[6],  c1.z));
        a = __fadd_rn(a, __fmul_rn(xc[7],  c1.w));
        a = __fadd_rn(a, __fmul_rn(xc[8],  c2.x));
        a = __fadd_rn(a, __fmul_rn(xc[9],  c2.y));
        a = __fadd_rn(a, __fmul_rn(xc[10], c2.z));
        a = __fadd_rn(a, __fmul_rn(xc[11], c2.w));
        a = __fadd_rn(a, __fmul_rn(xc[12], c3.x));
        a = __fadd_rn(a, __fmul_rn(xc[13], c3.y));
        a = __fadd_rn(a, __fmul_rn(xc[14], c3.z));
        a = __fadd_rn(a, __fmul_rn(xc[15], c3.w));
        acc[kk] = a;
      }
    }

    // epilogue: d = fl(fl(A - fl(2E)) + C); ascending k (first-occurrence)
#pragma unroll
    for (int kk = 0; kk < KT; ++kk) {
      float C = nlds[tile * KT + kk];  // wave-uniform ds_read broadcast
      float dist = __fadd_rn(__fsub_rn(A, __fmul_rn(2.0f, acc[kk])), C);
      if (dist < dmin) { dmin = dist; best = k0 + kk; }
    }
  }

  // distances always > 0 (A ~ 64 dominates) -> float bits order-preserving.
  cand[(size_t)quarter * BT + p] =
      ((uint64_t)__float_as_uint(dmin) << 32) | (uint32_t)best;

  // ---- last-of-4-siblings does the combine + gather + STE write ----
  __threadfence();     // make this thread's cand write device-visible
  __syncthreads();     // all threads' writes fenced before the flag bump
  if (tid == 0) lastFlag = (atomicAdd(&flags[pb], 1u) == NSPLIT - 1);
  __syncthreads();
  if (lastFlag) {
    __threadfence();   // acquire: siblings' cand writes are visible
    uint64_t m = cand[p];
#pragma unroll
    for (int q = 1; q < NSPLIT; ++q) {
      uint64_t c = cand[(size_t)q * BT + p];
      if (c < m) m = c;
    }
    const int bk = (int)(uint32_t)m;

    const vf4* qrow = (const vf4*)(cb + (size_t)bk * EMB_DIM);
    float* o0 = out + (size_t)b * EMB_DIM * TT + t;
    float* o1 = o0 + (size_t)BB * EMB_DIM * TT;
#pragma unroll
    for (int j = 0; j < 16; ++j) {
      vf4 q = qrow[j];
      size_t d0 = (size_t)(4 * j) * TT;
#pragma unroll
      for (int c = 0; c < 4; ++c) {
        size_t off = d0 + (size_t)c * TT;
        float qv = q[c];
        float xv = xb[off];
        // STE forward: fl(x + fl(q - x))
        o0[off] = __fadd_rn(xv, __fsub_rn(qv, xv));
        o1[off] = qv;
      }
    }
  }
}

extern "C" void kernel_launch(void* const* d_in, const int* in_sizes, int n_in,
                              void* d_out, int out_size, void* d_ws, size_t ws_size,
                              hipStream_t stream) {
  const float* x  = (const float*)d_in[0];   // [16, 64, 8192]
  const float* cb = (const float*)d_in[1];   // [512, 64]
  float* out = (float*)d_out;                // 2 x [16, 64, 8192]

  uint64_t* cand  = (uint64_t*)d_ws;                              // 4 MB
  uint32_t* flags = (uint32_t*)((char*)d_ws + (size_t)NSPLIT * BT * 8);

  hipMemsetAsync(flags, 0, (BT / 256) * sizeof(uint32_t), stream);
  vq_fused<<<(BT / 256) * NSPLIT, 256, 0, stream>>>(x, cb, cand, flags, out);
}